// Round 7
// baseline (435.916 us; speedup 1.0000x reference)
//
#include <hip/hip_runtime.h>
#include <hip/hip_cooperative_groups.h>
#include <stdint.h>

namespace cg = cooperative_groups;

#define Bn 4
#define An 3
#define Hn 168
#define Wn 256
#define Mn 32
#define HWn (Hn*Wn)
#define Nn (HWn*An)          // 129024
#define POS_CAP 8192
#define BND_CAP 2048
#define NPERIM 256
#define NPOSMAX 128
#define FG_THR 0.7f
#define BG_THR 0.3f
#define BETA (1.0f/9.0f)

#define NBLK 126             // blocks per image for anchor-parallel phases
#define GRID (Bn * NBLK)     // 504 blocks, 2/CU -> cooperative co-residency guaranteed
#define APT 4
#define STRIDE (NBLK * 256)  // 32256

// ---- workspace layout (uint32 word offsets) ----
#define OFF_KEYS   0            // Bn*2
#define OFF_COLMAX 8            // Bn*Mn = 128 (float bits, atomicMax)
#define OFF_POSCNT 136          // Bn
#define OFF_BNDCNT 140          // Bn
#define OFF_BOUND  144          // Bn
#define OFF_NEED   148          // Bn
#define OFF_COUNT  152          // 1
#define OFF_CLS    153          // 1 (float bits)
#define OFF_REG    154          // 1 (float bits)
#define OFF_DONE   155          // 1
#define ZERO_BEG   8
#define ZERO_END   160
#define OFF_PACK   4256         // Bn*Nn  (m | cat<<24)       -> 520352
#define OFF_PLIST  520352       // Bn*POS_CAP*2               -> 585888
#define OFF_BLIST  585888       // Bn*BND_CAP*2               -> 602272
#define OFF_PHIST  602272       // Bn*NBLK*1024 = 516096      -> 1118368
#define OFF_FHIST  1118368      // Bn*1024                    -> 1122464 (~4.5MB)

// ------------------- threefry2x32 (20 rounds) -------------------
__device__ __forceinline__ uint32_t rotl32(uint32_t v, int n) { return (v << n) | (v >> (32 - n)); }

__device__ __forceinline__ void tf2x32(uint32_t k0, uint32_t k1, uint32_t x0, uint32_t x1,
                                       uint32_t& o0, uint32_t& o1) {
    uint32_t k2 = k0 ^ k1 ^ 0x1BD11BDAu;
    x0 += k0; x1 += k1;
    x0 += x1; x1 = rotl32(x1, 13); x1 ^= x0;
    x0 += x1; x1 = rotl32(x1, 15); x1 ^= x0;
    x0 += x1; x1 = rotl32(x1, 26); x1 ^= x0;
    x0 += x1; x1 = rotl32(x1, 6);  x1 ^= x0;
    x0 += k1; x1 += k2 + 1u;
    x0 += x1; x1 = rotl32(x1, 17); x1 ^= x0;
    x0 += x1; x1 = rotl32(x1, 29); x1 ^= x0;
    x0 += x1; x1 = rotl32(x1, 16); x1 ^= x0;
    x0 += x1; x1 = rotl32(x1, 24); x1 ^= x0;
    x0 += k2; x1 += k0 + 2u;
    x0 += x1; x1 = rotl32(x1, 13); x1 ^= x0;
    x0 += x1; x1 = rotl32(x1, 15); x1 ^= x0;
    x0 += x1; x1 = rotl32(x1, 26); x1 ^= x0;
    x0 += x1; x1 = rotl32(x1, 6);  x1 ^= x0;
    x0 += k0; x1 += k1 + 3u;
    x0 += x1; x1 = rotl32(x1, 17); x1 ^= x0;
    x0 += x1; x1 = rotl32(x1, 29); x1 ^= x0;
    x0 += x1; x1 = rotl32(x1, 16); x1 ^= x0;
    x0 += x1; x1 = rotl32(x1, 24); x1 ^= x0;
    x0 += k1; x1 += k2 + 4u;
    x0 += x1; x1 = rotl32(x1, 13); x1 ^= x0;
    x0 += x1; x1 = rotl32(x1, 15); x1 ^= x0;
    x0 += x1; x1 = rotl32(x1, 26); x1 ^= x0;
    x0 += x1; x1 = rotl32(x1, 6);  x1 ^= x0;
    x0 += k2; x1 += k0 + 5u;
    o0 = x0; o1 = x1;
}

__device__ __forceinline__ uint32_t rng_m23(uint32_t k0, uint32_t k1, uint32_t i) {
    uint32_t o0, o1;
    tf2x32(k0, k1, 0u, i, o0, o1);
    return (o0 ^ o1) >> 9;
}

// ------------------- IoU (one definition -> bit-identical in both passes) ------------
__device__ __forceinline__ float iou_one(float a0, float a1, float a2, float a3,
                                         float t0, float t1, float t2, float t3) {
    float xtl = fmaxf(a0, t0), ytl = fmaxf(a1, t1);
    float xrb = fminf(a2, t2), yrb = fminf(a3, t3);
    float iw = fmaxf(xrb - xtl + 1.0f, 0.0f);
    float ih = fmaxf(yrb - ytl + 1.0f, 0.0f);
    float inter = iw * ih;
    float area1 = (a2 - a0 + 1.0f) * (a3 - a1 + 1.0f);
    float area2 = (t2 - t0 + 1.0f) * (t3 - t1 + 1.0f);
    return inter * __builtin_amdgcn_rcpf(area1 + area2 - inter);
}

__device__ __forceinline__ bool sel_less(uint2 a, uint2 b) {
    // larger priority m first; tie -> smaller index (JAX top_k order)
    return (a.x > b.x) || (a.x == b.x && a.y < b.y);
}

__device__ void bitonic_sort_shared(uint2* buf, int n) {   // n = pow2
    for (int k = 2; k <= n; k <<= 1) {
        for (int j = k >> 1; j > 0; j >>= 1) {
            for (int t = (int)threadIdx.x; t < n; t += 256) {
                int ixj = t ^ j;
                if (ixj > t) {
                    uint2 x = buf[t], y = buf[ixj];
                    bool up = ((t & k) == 0);
                    bool sw = up ? sel_less(y, x) : sel_less(x, y);
                    if (sw) { buf[t] = y; buf[ixj] = x; }
                }
            }
            __syncthreads();
        }
    }
}

// ===================== fused cooperative kernel =====================
__global__ void __launch_bounds__(256, 2)
rpn_fused(const float* __restrict__ anchors, const float* __restrict__ logits,
          const float* __restrict__ bregs, const float* __restrict__ sizes,
          const float* __restrict__ targets, uint32_t* __restrict__ ws,
          float* __restrict__ out) {
    cg::grid_group grid = cg::this_grid();
    __shared__ uint32_t smem[4096 + 256];    // 17408 B: buf(16KB) + red/csum(1KB)
    const int gid = blockIdx.x;
    const int tid = threadIdx.x;
    const int b = gid / NBLK;
    const int j = gid % NBLK;

    // ---------- phase 0: init control words + keys ----------
    if (gid == 0) {
        for (int w = ZERO_BEG + tid; w < ZERO_END; w += 256) ws[w] = 0u;
        if (tid == 0) {
            for (int bb = 0; bb < Bn; ++bb) {
                uint32_t o0, o1;
                tf2x32(0u, 42u, 0u, (uint32_t)bb, o0, o1);
                ws[OFF_KEYS + 2*bb] = o0; ws[OFF_KEYS + 2*bb + 1] = o1;
            }
        }
    }
    grid.sync();

    // ---------- phase A: per-target column max IoU ----------
    {
        float* part = (float*)smem;          // [4][Mn]
        int base = j * 256 + tid;
        float4 a[APT];
        #pragma unroll
        for (int k = 0; k < APT; ++k)
            a[k] = ((const float4*)anchors)[b * Nn + base + k * STRIDE];
        float cm[Mn];
        #pragma unroll 4
        for (int t = 0; t < Mn; ++t) {
            float4 tv = ((const float4*)targets)[b * Mn + t];
            float m0 = 0.0f;
            #pragma unroll
            for (int k = 0; k < APT; ++k)
                m0 = fmaxf(m0, iou_one(a[k].x, a[k].y, a[k].z, a[k].w, tv.x, tv.y, tv.z, tv.w));
            cm[t] = m0;
        }
        #pragma unroll
        for (int t = 0; t < Mn; ++t) {
            #pragma unroll
            for (int o = 32; o > 0; o >>= 1) cm[t] = fmaxf(cm[t], __shfl_xor(cm[t], o, 64));
        }
        int wid = tid >> 6, lane = tid & 63;
        if (lane == 0) {
            #pragma unroll
            for (int t = 0; t < Mn; ++t) part[wid * Mn + t] = cm[t];
        }
        __syncthreads();
        if (tid < Mn) {
            float v = fmaxf(fmaxf(part[0*Mn + tid], part[1*Mn + tid]),
                            fmaxf(part[2*Mn + tid], part[3*Mn + tid]));
            atomicMax(&ws[OFF_COLMAX + b * Mn + tid], __float_as_uint(v));
        }
    }
    grid.sync();

    // ---------- phase B: categorize + RNG + LDS hist + pos list ----------
    {
        uint32_t* lh = smem;                 // 1024-bucket block-local histogram
        #pragma unroll
        for (int q = 0; q < 4; ++q) lh[tid + 256 * q] = 0u;
        __syncthreads();
        int base = j * 256 + tid;
        float4 av[APT];
        #pragma unroll
        for (int k = 0; k < APT; ++k)
            av[k] = ((const float4*)anchors)[b * Nn + base + k * STRIDE];
        float rowmax[APT]; int ori[APT]; bool restore[APT];
        #pragma unroll
        for (int k = 0; k < APT; ++k) { rowmax[k] = -1.0f; ori[k] = 0; restore[k] = false; }
        #pragma unroll 4
        for (int t = 0; t < Mn; ++t) {
            float4 tv = ((const float4*)targets)[b * Mn + t];
            float cmf = __uint_as_float(ws[OFF_COLMAX + b * Mn + t]);
            #pragma unroll
            for (int k = 0; k < APT; ++k) {
                float iou = iou_one(av[k].x, av[k].y, av[k].z, av[k].w, tv.x, tv.y, tv.z, tv.w);
                if (iou > rowmax[k]) { rowmax[k] = iou; ori[k] = t; }
                restore[k] = restore[k] || (iou == cmf);
            }
        }
        float sh = sizes[b * 2 + 0], sw = sizes[b * 2 + 1];
        uint32_t key0 = ws[OFF_KEYS + 2 * b], key1 = ws[OFF_KEYS + 2 * b + 1];
        int lane = tid & 63;
        #pragma unroll
        for (int k = 0; k < APT; ++k) {
            int i = base + k * STRIDE;
            bool inside = (av[k].x >= 0.0f) && (av[k].y >= 0.0f) &&
                          (av[k].z <= sw - 1.0f) && (av[k].w <= sh - 1.0f);
            uint32_t cat = 0;
            if (inside) {
                if (restore[k] || rowmax[k] >= FG_THR) cat = 2;
                else if (rowmax[k] < BG_THR) cat = 1;
            }
            uint32_t m = rng_m23(key0, key1, (uint32_t)i);
            ws[OFF_PACK + b * Nn + i] = m | (cat << 24);
            // wave-aggregated ticketing: 1 atomic per wave per slot
            unsigned long long mask = __ballot(cat == 2u);
            if (mask) {
                int leader = __ffsll(mask) - 1;
                uint32_t bb = 0;
                if (lane == leader) bb = atomicAdd(&ws[OFF_POSCNT + b], (uint32_t)__popcll(mask));
                bb = __shfl(bb, leader, 64);
                if (cat == 2u) {
                    uint32_t p = bb + (uint32_t)__popcll(mask & ((1ull << lane) - 1ull));
                    if (p < POS_CAP) {
                        ws[OFF_PLIST + ((uint32_t)b * POS_CAP + p) * 2 + 0] = m;
                        ws[OFF_PLIST + ((uint32_t)b * POS_CAP + p) * 2 + 1] = (uint32_t)i | ((uint32_t)ori[k] << 17);
                    }
                }
            }
            if (cat == 1u) atomicAdd(&lh[m >> 13], 1u);
        }
        __syncthreads();
        uint32_t* slice = ws + OFF_PHIST + ((size_t)b * NBLK + j) * 1024;
        #pragma unroll
        for (int q = 0; q < 4; ++q) slice[tid + 256 * q] = lh[tid + 256 * q];
    }
    grid.sync();

    // ---------- phase C: parallel slice reduction (128 blocks) ----------
    if (gid < Bn * 32) {
        int cb = gid >> 5, j32 = gid & 31;
        int g = tid & 31, sub = tid >> 5;            // 8 subs x 32 buckets
        int bucket = j32 * 32 + g;
        const uint32_t* ph = ws + OFF_PHIST + (size_t)cb * NBLK * 1024;
        uint32_t acc = 0;
        for (int s = sub; s < NBLK; s += 8) acc += ph[(size_t)s * 1024 + bucket];
        smem[tid] = acc;
        __syncthreads();
        if (sub == 0) {
            #pragma unroll
            for (int q = 1; q < 8; ++q) acc += smem[g + 32 * q];
            ws[OFF_FHIST + cb * 1024 + bucket] = acc;
        }
    }
    grid.sync();

    // ---------- phase D: suffix scan + boundary (4 blocks) ----------
    if (gid < Bn) {
        uint32_t* csum = smem + 4096;
        uint4 h = ((const uint4*)(ws + OFF_FHIST + gid * 1024))[tid];
        uint32_t sum = h.x + h.y + h.z + h.w;
        csum[tid] = sum;
        __syncthreads();
        for (int off = 1; off < 256; off <<= 1) {
            uint32_t mine = csum[tid];
            uint32_t add = (tid + off < 256) ? csum[tid + off] : 0u;
            __syncthreads();
            csum[tid] = mine + add;
            __syncthreads();
        }
        uint32_t pc = ws[OFF_POSCNT + gid];
        int num_pos = (pc < (uint32_t)NPOSMAX) ? (int)pc : NPOSMAX;
        int k_neg = NPERIM - num_pos;
        uint32_t total = csum[0];
        if ((int)total < k_neg) {
            if (tid == 0) {
                ws[OFF_BOUND + gid] = 0xFFFFFFFFu;
                ws[OFF_NEED + gid] = 0u;
                atomicAdd(&ws[OFF_COUNT], (uint32_t)(num_pos + (int)total));
            }
        } else {
            uint32_t incl = csum[tid];
            uint32_t next = (tid < 255) ? csum[tid + 1] : 0u;
            if ((int)incl >= k_neg && (int)next < k_neg) {
                int cum = (int)next;
                uint32_t hv[4] = { h.x, h.y, h.z, h.w };
                int boundary = -1, needed = 0;
                #pragma unroll
                for (int q = 3; q >= 0; --q) {
                    int c = (int)hv[q];
                    if (cum + c >= k_neg) { boundary = 4 * tid + q; needed = k_neg - cum; break; }
                    cum += c;
                }
                ws[OFF_BOUND + gid] = (uint32_t)boundary;
                ws[OFF_NEED + gid] = (uint32_t)needed;
                atomicAdd(&ws[OFF_COUNT], (uint32_t)(num_pos + k_neg));
            }
        }
    }
    grid.sync();

    // ---------- phase E: BCE over selected negatives + boundary gather ----------
    {
        float* red = (float*)(smem + 4096);
        int bd = (int)(int32_t)ws[OFF_BOUND + b];
        float local = 0.0f;
        #pragma unroll
        for (int q = 0; q < 4; ++q) {
            int i = j * 1024 + tid + 256 * q;
            uint32_t p = ws[OFF_PACK + b * Nn + i];
            if ((p >> 24) == 1u) {
                uint32_t m = p & 0x7FFFFFu;
                int bk = (int)(m >> 13);
                if (bk > bd) {
                    int a = i % An, hw = i / An;
                    float l = logits[(b * An + a) * HWn + hw];
                    local += fmaxf(l, 0.0f) + log1pf(expf(-fabsf(l)));   // BCE(l,0)
                } else if (bk == bd) {
                    uint32_t q2 = atomicAdd(&ws[OFF_BNDCNT + b], 1u);
                    if (q2 < BND_CAP) {
                        ws[OFF_BLIST + ((uint32_t)b * BND_CAP + q2) * 2 + 0] = m;
                        ws[OFF_BLIST + ((uint32_t)b * BND_CAP + q2) * 2 + 1] = (uint32_t)i;
                    }
                }
            }
        }
        red[tid] = local;
        __syncthreads();
        for (int s = 128; s > 0; s >>= 1) {
            if (tid < s) red[tid] += red[tid + s];
            __syncthreads();
        }
        if (tid == 0 && red[0] != 0.0f) atomicAdd((float*)&ws[OFF_CLS], red[0]);
    }
    grid.sync();

    // ---------- phase F: per-image finalize + output (4 blocks) ----------
    if (gid < Bn) {
        int fb = gid;
        uint2* buf = (uint2*)smem;
        float* red = (float*)(smem + 4096);
        float cls = 0.0f, reg = 0.0f;

        uint32_t pcu = ws[OFF_POSCNT + fb];
        int pc = (pcu < (uint32_t)POS_CAP) ? (int)pcu : POS_CAP;
        const uint32_t* plist = ws + OFF_PLIST + (size_t)fb * POS_CAP * 2;
        int psel = (pc < NPOSMAX) ? pc : NPOSMAX;
        bool use_buf = false;
        if (pc > NPOSMAX) {
            int n = (pc < BND_CAP) ? pc : BND_CAP;
            for (int t = tid; t < n; t += 256) buf[t] = make_uint2(plist[2*t], plist[2*t+1]);
            int npad = 1; while (npad < n) npad <<= 1;
            for (int t = tid; t < npad; t += 256) if (t >= n) buf[t] = make_uint2(0u, 0xFFFFFFFFu);
            __syncthreads();
            bitonic_sort_shared(buf, npad);
            use_buf = true;
            psel = (NPOSMAX < n) ? NPOSMAX : n;
        }
        for (int t = tid; t < psel; t += 256) {
            uint32_t packed = use_buf ? buf[t].y : plist[2*t+1];
            int i = (int)(packed & 0x1FFFFu);
            int ori = (int)(packed >> 17);
            int a = i % An, hw = i / An;
            float l = logits[(fb * An + a) * HWn + hw];
            cls += fmaxf(l, 0.0f) - l + log1pf(expf(-fabsf(l)));   // BCE(l,1)
            float4 av = ((const float4*)anchors)[fb * Nn + i];
            float4 tv = ((const float4*)targets)[fb * Mn + ori];
            float aws = av.z - av.x + 1.0f, ahs = av.w - av.y + 1.0f;
            float axc = av.x + 0.5f * aws, ayc = av.y + 0.5f * ahs;
            float tws = tv.z - tv.x + 1.0f, ths = tv.w - tv.y + 1.0f;
            float txc = tv.x + 0.5f * tws, tyc = tv.y + 0.5f * ths;
            float off0 = (txc - axc) / aws;
            float off1 = (tyc - ayc) / ahs;
            float off2 = logf(tws / aws);
            float off3 = logf(ths / ahs);
            float br0 = bregs[(fb * 12 + a * 4 + 0) * HWn + hw];
            float br1 = bregs[(fb * 12 + a * 4 + 1) * HWn + hw];
            float br2 = bregs[(fb * 12 + a * 4 + 2) * HWn + hw];
            float br3 = bregs[(fb * 12 + a * 4 + 3) * HWn + hw];
            float d;
            d = fabsf(br0 - off0); reg += (d < BETA) ? 0.5f * d * d / BETA : d - 0.5f * BETA;
            d = fabsf(br1 - off1); reg += (d < BETA) ? 0.5f * d * d / BETA : d - 0.5f * BETA;
            d = fabsf(br2 - off2); reg += (d < BETA) ? 0.5f * d * d / BETA : d - 0.5f * BETA;
            d = fabsf(br3 - off3); reg += (d < BETA) ? 0.5f * d * d / BETA : d - 0.5f * BETA;
        }
        __syncthreads();

        int need = (int)ws[OFF_NEED + fb];
        if (need > 0) {
            uint32_t nbu = ws[OFF_BNDCNT + fb];
            int nb = (nbu < (uint32_t)BND_CAP) ? (int)nbu : BND_CAP;
            const uint32_t* blist = ws + OFF_BLIST + (size_t)fb * BND_CAP * 2;
            for (int t = tid; t < nb; t += 256) buf[t] = make_uint2(blist[2*t], blist[2*t+1]);
            int npad = 1; while (npad < nb) npad <<= 1;
            for (int t = tid; t < npad; t += 256) if (t >= nb) buf[t] = make_uint2(0u, 0xFFFFFFFFu);
            __syncthreads();
            bitonic_sort_shared(buf, npad);
            int sel = (need < nb) ? need : nb;
            for (int t = tid; t < sel; t += 256) {
                int i = (int)buf[t].y;
                int a = i % An, hw = i / An;
                float l = logits[(fb * An + a) * HWn + hw];
                cls += fmaxf(l, 0.0f) + log1pf(expf(-fabsf(l)));   // BCE(l,0)
            }
        }

        red[tid] = cls;
        __syncthreads();
        for (int s = 128; s > 0; s >>= 1) {
            if (tid < s) red[tid] += red[tid + s];
            __syncthreads();
        }
        if (tid == 0 && red[0] != 0.0f) atomicAdd((float*)&ws[OFF_CLS], red[0]);
        __syncthreads();
        red[tid] = reg;
        __syncthreads();
        for (int s = 128; s > 0; s >>= 1) {
            if (tid < s) red[tid] += red[tid + s];
            __syncthreads();
        }
        if (tid == 0) {
            if (red[0] != 0.0f) atomicAdd((float*)&ws[OFF_REG], red[0]);
            __threadfence();
            uint32_t old = atomicAdd(&ws[OFF_DONE], 1u);
            if (old == Bn - 1) {
                float cls_tot = __uint_as_float(atomicAdd(&ws[OFF_CLS], 0u));
                float reg_tot = __uint_as_float(atomicAdd(&ws[OFF_REG], 0u));
                float cnt = (float)atomicAdd(&ws[OFF_COUNT], 0u);
                out[0] = cls_tot / cnt;
                out[1] = reg_tot / cnt;
            }
        }
    }
}

extern "C" void kernel_launch(void* const* d_in, const int* in_sizes, int n_in,
                              void* d_out, int out_size, void* d_ws, size_t ws_size,
                              hipStream_t stream) {
    const float* anchors = (const float*)d_in[0];   // [B, N, 4]
    const float* logits  = (const float*)d_in[1];   // [B, A, H, W]
    const float* bregs   = (const float*)d_in[2];   // [B, 4A, H, W]
    const float* sizes   = (const float*)d_in[3];   // [B, 2]
    const float* targets = (const float*)d_in[4];   // [B, M, 4]
    float* out = (float*)d_out;
    uint32_t* ws = (uint32_t*)d_ws;

    void* args[] = { (void*)&anchors, (void*)&logits, (void*)&bregs,
                     (void*)&sizes, (void*)&targets, (void*)&ws, (void*)&out };
    hipLaunchCooperativeKernel((const void*)rpn_fused, dim3(GRID), dim3(256),
                               args, 0, stream);
}

// Round 8
// 248.704 us; speedup vs baseline: 1.7528x; 1.7528x over previous
//
#include <hip/hip_runtime.h>
#include <stdint.h>

#define Bn 4
#define An 3
#define Hn 168
#define Wn 256
#define Mn 32
#define HWn (Hn*Wn)
#define Nn (HWn*An)          // 129024
#define POS_CAP 8192
#define BND_CAP 2048
#define NEG_CAP 131072       // >= Nn, can never truncate
#define NPERIM 256
#define NPOSMAX 128
#define FG_THR 0.7f
#define BG_THR 0.3f
#define BETA (1.0f/9.0f)

#define NBLK 126             // blocks per image for anchor-parallel kernels
#define APT 4                // anchors/thread (measured best: ILP > occupancy here)
#define STRIDE (NBLK * 256)  // 32256

// ---- workspace layout (uint32 word offsets) ----
#define OFF_POSCNT 0            // Bn
#define OFF_NEGCNT 4            // Bn
#define OFF_BNDCNT 8            // Bn
#define OFF_BOUND  12           // Bn (int32, -1 = all negatives selected)
#define OFF_NEED   16           // Bn
#define OFF_COUNT  20           // 1
#define OFF_CLS    21           // 1 (float bits)
#define OFF_REG    22           // 1 (float bits)
#define OFF_DONE   23           // 1
#define OFF_KEYS   24           // Bn*2
#define OFF_PCM    32           // Bn*NBLK*Mn = 16128      -> 16160  (partial colmax, float bits)
#define OFF_PHIST  16160        // Bn*NBLK*1024 = 516096   -> 532256
#define OFF_FHIST  532256       // Bn*1024                 -> 536352
#define OFF_PLIST  536352       // Bn*POS_CAP*2            -> 601888
#define OFF_BLIST  601888       // Bn*BND_CAP*2            -> 618272
#define OFF_NLIST  618272       // Bn*NEG_CAP*2            -> 1666848 (~6.7MB)

// ------------------- threefry2x32 (20 rounds) -------------------
__device__ __forceinline__ uint32_t rotl32(uint32_t v, int n) { return (v << n) | (v >> (32 - n)); }

__device__ __forceinline__ void tf2x32(uint32_t k0, uint32_t k1, uint32_t x0, uint32_t x1,
                                       uint32_t& o0, uint32_t& o1) {
    uint32_t k2 = k0 ^ k1 ^ 0x1BD11BDAu;
    x0 += k0; x1 += k1;
    x0 += x1; x1 = rotl32(x1, 13); x1 ^= x0;
    x0 += x1; x1 = rotl32(x1, 15); x1 ^= x0;
    x0 += x1; x1 = rotl32(x1, 26); x1 ^= x0;
    x0 += x1; x1 = rotl32(x1, 6);  x1 ^= x0;
    x0 += k1; x1 += k2 + 1u;
    x0 += x1; x1 = rotl32(x1, 17); x1 ^= x0;
    x0 += x1; x1 = rotl32(x1, 29); x1 ^= x0;
    x0 += x1; x1 = rotl32(x1, 16); x1 ^= x0;
    x0 += x1; x1 = rotl32(x1, 24); x1 ^= x0;
    x0 += k2; x1 += k0 + 2u;
    x0 += x1; x1 = rotl32(x1, 13); x1 ^= x0;
    x0 += x1; x1 = rotl32(x1, 15); x1 ^= x0;
    x0 += x1; x1 = rotl32(x1, 26); x1 ^= x0;
    x0 += x1; x1 = rotl32(x1, 6);  x1 ^= x0;
    x0 += k0; x1 += k1 + 3u;
    x0 += x1; x1 = rotl32(x1, 17); x1 ^= x0;
    x0 += x1; x1 = rotl32(x1, 29); x1 ^= x0;
    x0 += x1; x1 = rotl32(x1, 16); x1 ^= x0;
    x0 += x1; x1 = rotl32(x1, 24); x1 ^= x0;
    x0 += k1; x1 += k2 + 4u;
    x0 += x1; x1 = rotl32(x1, 13); x1 ^= x0;
    x0 += x1; x1 = rotl32(x1, 15); x1 ^= x0;
    x0 += x1; x1 = rotl32(x1, 26); x1 ^= x0;
    x0 += x1; x1 = rotl32(x1, 6);  x1 ^= x0;
    x0 += k2; x1 += k0 + 5u;
    o0 = x0; o1 = x1;
}

__device__ __forceinline__ uint32_t rng_m23(uint32_t k0, uint32_t k1, uint32_t i) {
    uint32_t o0, o1;
    tf2x32(k0, k1, 0u, i, o0, o1);
    return (o0 ^ o1) >> 9;
}

// ------------------- IoU (one definition -> bit-identical in both passes) ------------
__device__ __forceinline__ float iou_one(float a0, float a1, float a2, float a3,
                                         float t0, float t1, float t2, float t3) {
    float xtl = fmaxf(a0, t0), ytl = fmaxf(a1, t1);
    float xrb = fminf(a2, t2), yrb = fminf(a3, t3);
    float iw = fmaxf(xrb - xtl + 1.0f, 0.0f);
    float ih = fmaxf(yrb - ytl + 1.0f, 0.0f);
    float inter = iw * ih;
    float area1 = (a2 - a0 + 1.0f) * (a3 - a1 + 1.0f);
    float area2 = (t2 - t0 + 1.0f) * (t3 - t1 + 1.0f);
    return inter * __builtin_amdgcn_rcpf(area1 + area2 - inter);
}

// ------------------- K1: partial colmax per block (no atomics, no pre-zero) ----------
__global__ void __launch_bounds__(256) k1_colmax(const float* __restrict__ anchors,
                                                 const float* __restrict__ targets,
                                                 uint32_t* __restrict__ ws) {
    int b = blockIdx.y, j = blockIdx.x, tid = threadIdx.x;
    // fold old k0 into block (0,0): zero control words + derive keys.
    if (b == 0 && j == 0) {
        if (tid < 24) ws[tid] = 0u;
        if (tid == 0) {
            for (int bb = 0; bb < Bn; ++bb) {
                uint32_t o0, o1;
                tf2x32(0u, 42u, 0u, (uint32_t)bb, o0, o1);
                ws[OFF_KEYS + 2*bb] = o0; ws[OFF_KEYS + 2*bb + 1] = o1;
            }
        }
    }
    __shared__ float part[4][Mn];
    int base = j * 256 + tid;
    float4 a[APT];
    #pragma unroll
    for (int k = 0; k < APT; ++k)
        a[k] = ((const float4*)anchors)[b * Nn + base + k * STRIDE];
    float cm[Mn];
    #pragma unroll 4
    for (int t = 0; t < Mn; ++t) {
        float4 tv = ((const float4*)targets)[b * Mn + t];
        float m0 = 0.0f;
        #pragma unroll
        for (int k = 0; k < APT; ++k)
            m0 = fmaxf(m0, iou_one(a[k].x, a[k].y, a[k].z, a[k].w, tv.x, tv.y, tv.z, tv.w));
        cm[t] = m0;
    }
    #pragma unroll
    for (int t = 0; t < Mn; ++t) {
        #pragma unroll
        for (int o = 32; o > 0; o >>= 1) cm[t] = fmaxf(cm[t], __shfl_xor(cm[t], o, 64));
    }
    int wid = tid >> 6, lane = tid & 63;
    if (lane == 0) {
        #pragma unroll
        for (int t = 0; t < Mn; ++t) part[wid][t] = cm[t];
    }
    __syncthreads();
    if (tid < Mn) {
        float v = fmaxf(fmaxf(part[0][tid], part[1][tid]),
                        fmaxf(part[2][tid], part[3][tid]));
        ws[OFF_PCM + ((size_t)b * NBLK + j) * Mn + tid] = __float_as_uint(v);
    }
}

// ------------------- K2: categorize + RNG + LDS hist + compact pos/neg lists --------
__global__ void __launch_bounds__(256) k2_cat(const float* __restrict__ anchors,
                                              const float* __restrict__ targets,
                                              const float* __restrict__ sizes,
                                              uint32_t* __restrict__ ws) {
    int b = blockIdx.y, j = blockIdx.x, tid = threadIdx.x;
    __shared__ float cmf[Mn];
    __shared__ float redf[256];
    __shared__ uint32_t lh[1024];
    // prologue: reduce per-block partial colmax (exact: max is assoc/comm)
    {
        int t = tid & 31, sub = tid >> 5;
        float acc = 0.0f;
        for (int jj = sub; jj < NBLK; jj += 8)
            acc = fmaxf(acc, __uint_as_float(ws[OFF_PCM + ((size_t)b * NBLK + jj) * Mn + t]));
        redf[tid] = acc;
        __syncthreads();
        if (sub == 0) {
            #pragma unroll
            for (int q = 1; q < 8; ++q) acc = fmaxf(acc, redf[t + 32 * q]);
            cmf[t] = acc;
        }
    }
    #pragma unroll
    for (int q = 0; q < 4; ++q) lh[tid + 256 * q] = 0u;
    __syncthreads();

    int base = j * 256 + tid;
    float4 av[APT];
    #pragma unroll
    for (int k = 0; k < APT; ++k)
        av[k] = ((const float4*)anchors)[b * Nn + base + k * STRIDE];
    float rowmax[APT]; int ori[APT]; bool restore[APT];
    #pragma unroll
    for (int k = 0; k < APT; ++k) { rowmax[k] = -1.0f; ori[k] = 0; restore[k] = false; }
    #pragma unroll 4
    for (int t = 0; t < Mn; ++t) {
        float4 tv = ((const float4*)targets)[b * Mn + t];
        float cmv = cmf[t];   // LDS broadcast (same address across wave: free)
        #pragma unroll
        for (int k = 0; k < APT; ++k) {
            float iou = iou_one(av[k].x, av[k].y, av[k].z, av[k].w, tv.x, tv.y, tv.z, tv.w);
            if (iou > rowmax[k]) { rowmax[k] = iou; ori[k] = t; }
            restore[k] = restore[k] || (iou == cmv);
        }
    }
    float sh = sizes[b * 2 + 0], sw = sizes[b * 2 + 1];
    uint32_t key0 = ws[OFF_KEYS + 2 * b], key1 = ws[OFF_KEYS + 2 * b + 1];
    int lane = tid & 63;
    unsigned long long lt_mask = (lane == 63) ? 0x7FFFFFFFFFFFFFFFull : ((1ull << lane) - 1ull);
    #pragma unroll
    for (int k = 0; k < APT; ++k) {
        int i = base + k * STRIDE;
        bool inside = (av[k].x >= 0.0f) && (av[k].y >= 0.0f) &&
                      (av[k].z <= sw - 1.0f) && (av[k].w <= sh - 1.0f);
        uint32_t cat = 0;
        if (inside) {
            if (restore[k] || rowmax[k] >= FG_THR) cat = 2;
            else if (rowmax[k] < BG_THR) cat = 1;
        }
        uint32_t m = rng_m23(key0, key1, (uint32_t)i);
        // wave-aggregated ticketing: one atomic per wave per list
        unsigned long long pmask = __ballot(cat == 2u);
        if (pmask) {
            int leader = __ffsll((long long)pmask) - 1;
            uint32_t bb = 0;
            if (lane == leader) bb = atomicAdd(&ws[OFF_POSCNT + b], (uint32_t)__popcll(pmask));
            bb = __shfl(bb, leader, 64);
            if (cat == 2u) {
                uint32_t p = bb + (uint32_t)__popcll(pmask & lt_mask);
                if (p < POS_CAP)
                    ((uint2*)(ws + OFF_PLIST))[(size_t)b * POS_CAP + p] =
                        make_uint2(m, (uint32_t)i | ((uint32_t)ori[k] << 17));
            }
        }
        unsigned long long nmask = __ballot(cat == 1u);
        if (nmask) {
            int leader = __ffsll((long long)nmask) - 1;
            uint32_t bb = 0;
            if (lane == leader) bb = atomicAdd(&ws[OFF_NEGCNT + b], (uint32_t)__popcll(nmask));
            bb = __shfl(bb, leader, 64);
            if (cat == 1u) {
                uint32_t p = bb + (uint32_t)__popcll(nmask & lt_mask);
                ((uint2*)(ws + OFF_NLIST))[(size_t)b * NEG_CAP + p] = make_uint2(m, (uint32_t)i);
                atomicAdd(&lh[m >> 13], 1u);
            }
        }
    }
    __syncthreads();
    uint32_t* slice = ws + OFF_PHIST + ((size_t)b * NBLK + j) * 1024;
    #pragma unroll
    for (int q = 0; q < 4; ++q) slice[tid + 256 * q] = lh[tid + 256 * q];
}

// ------------------- K2.5: reduce slices + suffix scan + boundary -------------------
__global__ void __launch_bounds__(256) k25_bound(uint32_t* __restrict__ ws) {
    int b = blockIdx.x, t = threadIdx.x;
    __shared__ uint32_t csum[256];
    uint4 h = make_uint4(0, 0, 0, 0);
    const uint32_t* ph = ws + OFF_PHIST + (size_t)b * NBLK * 1024;
    for (int s = 0; s < NBLK; ++s) {
        uint4 v = ((const uint4*)(ph + (size_t)s * 1024))[t];
        h.x += v.x; h.y += v.y; h.z += v.z; h.w += v.w;
    }
    uint32_t sum = h.x + h.y + h.z + h.w;
    csum[t] = sum;
    __syncthreads();
    for (int off = 1; off < 256; off <<= 1) {
        uint32_t mine = csum[t];
        uint32_t add = (t + off < 256) ? csum[t + off] : 0u;
        __syncthreads();
        csum[t] = mine + add;
        __syncthreads();
    }
    uint32_t pc = ws[OFF_POSCNT + b];
    int num_pos = (pc < (uint32_t)NPOSMAX) ? (int)pc : NPOSMAX;
    int k_neg = NPERIM - num_pos;
    uint32_t total = csum[0];
    if ((int)total < k_neg) {
        if (t == 0) {
            ws[OFF_BOUND + b] = 0xFFFFFFFFu;
            ws[OFF_NEED + b] = 0u;
            atomicAdd(&ws[OFF_COUNT], (uint32_t)(num_pos + (int)total));
        }
        return;
    }
    uint32_t incl = csum[t];
    uint32_t next = (t < 255) ? csum[t + 1] : 0u;
    if ((int)incl >= k_neg && (int)next < k_neg) {
        int cum = (int)next;
        uint32_t hv[4] = { h.x, h.y, h.z, h.w };
        int boundary = -1, needed = 0;
        #pragma unroll
        for (int q = 3; q >= 0; --q) {
            int c = (int)hv[q];
            if (cum + c >= k_neg) { boundary = 4 * t + q; needed = k_neg - cum; break; }
            cum += c;
        }
        ws[OFF_BOUND + b] = (uint32_t)boundary;
        ws[OFF_NEED + b] = (uint32_t)needed;
        atomicAdd(&ws[OFF_COUNT], (uint32_t)(num_pos + k_neg));
    }
}

// ------------------- K3: dense scan of compact negative list -------------------
__global__ void __launch_bounds__(256) k3_neg(const float* __restrict__ logits,
                                              uint32_t* __restrict__ ws) {
    int b = blockIdx.y;
    int bd = (int)(int32_t)ws[OFF_BOUND + b];     // uniform
    int cnt = (int)ws[OFF_NEGCNT + b];            // uniform (<= Nn < NEG_CAP)
    const uint2* nlist = (const uint2*)(ws + OFF_NLIST) + (size_t)b * NEG_CAP;
    float local = 0.0f;
    for (int idx = blockIdx.x * 256 + (int)threadIdx.x; idx < cnt; idx += NBLK * 256) {
        uint2 e = nlist[idx];
        int bk = (int)(e.x >> 13);
        if (bk > bd) {
            int i = (int)e.y;
            int a = i % An, hw = i / An;
            float l = logits[(b * An + a) * HWn + hw];
            local += fmaxf(l, 0.0f) + log1pf(expf(-fabsf(l)));   // BCE(l,0)
        } else if (bk == bd) {
            uint32_t q = atomicAdd(&ws[OFF_BNDCNT + b], 1u);
            if (q < BND_CAP)
                ((uint2*)(ws + OFF_BLIST))[(size_t)b * BND_CAP + q] = e;
        }
    }
    __shared__ float red[256];
    red[threadIdx.x] = local;
    __syncthreads();
    for (int s = 128; s > 0; s >>= 1) {
        if ((int)threadIdx.x < s) red[threadIdx.x] += red[threadIdx.x + s];
        __syncthreads();
    }
    if (threadIdx.x == 0 && red[0] != 0.0f) atomicAdd((float*)&ws[OFF_CLS], red[0]);
}

// ------------------- K4: per-image finalize + output -------------------
__device__ __forceinline__ bool sel_less(uint2 a, uint2 b) {
    // larger priority m first; tie -> smaller index (JAX top_k order)
    return (a.x > b.x) || (a.x == b.x && a.y < b.y);
}

__device__ void bitonic_sort_shared(uint2* buf, int n) {   // n = pow2
    for (int k = 2; k <= n; k <<= 1) {
        for (int j = k >> 1; j > 0; j >>= 1) {
            for (int t = (int)threadIdx.x; t < n; t += 256) {
                int ixj = t ^ j;
                if (ixj > t) {
                    uint2 x = buf[t], y = buf[ixj];
                    bool up = ((t & k) == 0);
                    bool sw = up ? sel_less(y, x) : sel_less(x, y);
                    if (sw) { buf[t] = y; buf[ixj] = x; }
                }
            }
            __syncthreads();
        }
    }
}

__global__ void __launch_bounds__(256) k4_final(const float* __restrict__ anchors,
                                                const float* __restrict__ targets,
                                                const float* __restrict__ logits,
                                                const float* __restrict__ bregs,
                                                uint32_t* __restrict__ ws,
                                                float* __restrict__ out) {
    int b = blockIdx.x, tid = threadIdx.x;
    __shared__ uint2 buf[BND_CAP];
    __shared__ float red[256];
    float cls = 0.0f, reg = 0.0f;

    uint32_t pcu = ws[OFF_POSCNT + b];
    int pc = (pcu < (uint32_t)POS_CAP) ? (int)pcu : POS_CAP;
    const uint2* plist = (const uint2*)(ws + OFF_PLIST) + (size_t)b * POS_CAP;
    int psel = (pc < NPOSMAX) ? pc : NPOSMAX;
    bool use_buf = false;
    if (pc > NPOSMAX) {
        int n = (pc < BND_CAP) ? pc : BND_CAP;
        for (int t = tid; t < n; t += 256) buf[t] = plist[t];
        int npad = 1; while (npad < n) npad <<= 1;
        for (int t = tid; t < npad; t += 256) if (t >= n) buf[t] = make_uint2(0u, 0xFFFFFFFFu);
        __syncthreads();
        bitonic_sort_shared(buf, npad);
        use_buf = true;
        psel = (NPOSMAX < n) ? NPOSMAX : n;
    }
    for (int t = tid; t < psel; t += 256) {
        uint32_t packed = use_buf ? buf[t].y : plist[t].y;
        int i = (int)(packed & 0x1FFFFu);
        int ori = (int)(packed >> 17);
        int a = i % An, hw = i / An;
        float l = logits[(b * An + a) * HWn + hw];
        cls += fmaxf(l, 0.0f) - l + log1pf(expf(-fabsf(l)));   // BCE(l,1)
        float4 av = ((const float4*)anchors)[b * Nn + i];
        float4 tv = ((const float4*)targets)[b * Mn + ori];
        float aws = av.z - av.x + 1.0f, ahs = av.w - av.y + 1.0f;
        float axc = av.x + 0.5f * aws, ayc = av.y + 0.5f * ahs;
        float tws = tv.z - tv.x + 1.0f, ths = tv.w - tv.y + 1.0f;
        float txc = tv.x + 0.5f * tws, tyc = tv.y + 0.5f * ths;
        float off0 = (txc - axc) / aws;
        float off1 = (tyc - ayc) / ahs;
        float off2 = logf(tws / aws);
        float off3 = logf(ths / ahs);
        float br0 = bregs[(b * 12 + a * 4 + 0) * HWn + hw];
        float br1 = bregs[(b * 12 + a * 4 + 1) * HWn + hw];
        float br2 = bregs[(b * 12 + a * 4 + 2) * HWn + hw];
        float br3 = bregs[(b * 12 + a * 4 + 3) * HWn + hw];
        float d;
        d = fabsf(br0 - off0); reg += (d < BETA) ? 0.5f * d * d / BETA : d - 0.5f * BETA;
        d = fabsf(br1 - off1); reg += (d < BETA) ? 0.5f * d * d / BETA : d - 0.5f * BETA;
        d = fabsf(br2 - off2); reg += (d < BETA) ? 0.5f * d * d / BETA : d - 0.5f * BETA;
        d = fabsf(br3 - off3); reg += (d < BETA) ? 0.5f * d * d / BETA : d - 0.5f * BETA;
    }
    __syncthreads();

    int need = (int)ws[OFF_NEED + b];
    if (need > 0) {
        uint32_t nbu = ws[OFF_BNDCNT + b];
        int nb = (nbu < (uint32_t)BND_CAP) ? (int)nbu : BND_CAP;
        const uint2* blist = (const uint2*)(ws + OFF_BLIST) + (size_t)b * BND_CAP;
        for (int t = tid; t < nb; t += 256) buf[t] = blist[t];
        int npad = 1; while (npad < nb) npad <<= 1;
        for (int t = tid; t < npad; t += 256) if (t >= nb) buf[t] = make_uint2(0u, 0xFFFFFFFFu);
        __syncthreads();
        bitonic_sort_shared(buf, npad);
        int sel = (need < nb) ? need : nb;
        for (int t = tid; t < sel; t += 256) {
            int i = (int)buf[t].y;
            int a = i % An, hw = i / An;
            float l = logits[(b * An + a) * HWn + hw];
            cls += fmaxf(l, 0.0f) + log1pf(expf(-fabsf(l)));   // BCE(l,0)
        }
    }

    red[tid] = cls;
    __syncthreads();
    for (int s = 128; s > 0; s >>= 1) {
        if (tid < s) red[tid] += red[tid + s];
        __syncthreads();
    }
    if (tid == 0 && red[0] != 0.0f) atomicAdd((float*)&ws[OFF_CLS], red[0]);
    __syncthreads();
    red[tid] = reg;
    __syncthreads();
    for (int s = 128; s > 0; s >>= 1) {
        if (tid < s) red[tid] += red[tid + s];
        __syncthreads();
    }
    if (tid == 0) {
        if (red[0] != 0.0f) atomicAdd((float*)&ws[OFF_REG], red[0]);
        __threadfence();
        uint32_t old = atomicAdd(&ws[OFF_DONE], 1u);
        if (old == Bn - 1) {
            float cls_tot = __uint_as_float(atomicAdd(&ws[OFF_CLS], 0u));
            float reg_tot = __uint_as_float(atomicAdd(&ws[OFF_REG], 0u));
            float cnt = (float)atomicAdd(&ws[OFF_COUNT], 0u);
            out[0] = cls_tot / cnt;
            out[1] = reg_tot / cnt;
        }
    }
}

extern "C" void kernel_launch(void* const* d_in, const int* in_sizes, int n_in,
                              void* d_out, int out_size, void* d_ws, size_t ws_size,
                              hipStream_t stream) {
    const float* anchors = (const float*)d_in[0];   // [B, N, 4]
    const float* logits  = (const float*)d_in[1];   // [B, A, H, W]
    const float* bregs   = (const float*)d_in[2];   // [B, 4A, H, W]
    const float* sizes   = (const float*)d_in[3];   // [B, 2]
    const float* targets = (const float*)d_in[4];   // [B, M, 4]
    float* out = (float*)d_out;
    uint32_t* ws = (uint32_t*)d_ws;

    k1_colmax<<<dim3(NBLK, Bn), dim3(256), 0, stream>>>(anchors, targets, ws);
    k2_cat<<<dim3(NBLK, Bn), dim3(256), 0, stream>>>(anchors, targets, sizes, ws);
    k25_bound<<<dim3(Bn), dim3(256), 0, stream>>>(ws);
    k3_neg<<<dim3(NBLK, Bn), dim3(256), 0, stream>>>(logits, ws);
    k4_final<<<dim3(Bn), dim3(256), 0, stream>>>(anchors, targets, logits, bregs, ws, out);
}

// Round 9
// 157.039 us; speedup vs baseline: 2.7758x; 1.5837x over previous
//
#include <hip/hip_runtime.h>
#include <stdint.h>

#define Bn 4
#define An 3
#define Hn 168
#define Wn 256
#define Mn 32
#define HWn (Hn*Wn)
#define Nn (HWn*An)          // 129024
#define POS_CAP 8192
#define BND_CAP 2048
#define NPERIM 256
#define NPOSMAX 128
#define FG_THR 0.7f
#define BG_THR 0.3f
#define BETA (1.0f/9.0f)

#define NBLK 126             // blocks per image for anchor-parallel kernels
#define APT 4                // anchors/thread (measured best: ILP > occupancy here)
#define STRIDE (NBLK * 256)  // 32256
#define SEG 1024             // NLIST segment per block == anchors per block (no overflow)

// ---- workspace layout (uint32 word offsets) ----
#define OFF_POSCNT 0            // Bn
#define OFF_BNDCNT 4            // Bn
#define OFF_BOUND  8            // Bn (int32, -1 = all negatives selected)
#define OFF_NEED   12           // Bn
#define OFF_COUNT  16           // 1
#define OFF_CLS    17           // 1 (float bits)
#define OFF_REG    18           // 1 (float bits)
#define OFF_DONE   19           // 1
#define OFF_KEYS   24           // Bn*2
#define OFF_PCM    32           // Bn*NBLK*Mn = 16128         -> 16160 (partial colmax bits)
#define OFF_NSEGC  16160        // Bn*NBLK = 504              -> 16664 (per-segment neg counts)
#define OFF_PHIST  16664        // Bn*NBLK*1024 = 516096      -> 532760
#define OFF_PLIST  532760       // Bn*POS_CAP*2               -> 598296
#define OFF_BLIST  598296       // Bn*BND_CAP*2               -> 614680
#define OFF_NLIST  614680       // Bn*NBLK*SEG*2 = 1032192    -> 1646872 (~6.6MB)

// ------------------- threefry2x32 (20 rounds) -------------------
__device__ __forceinline__ uint32_t rotl32(uint32_t v, int n) { return (v << n) | (v >> (32 - n)); }

__device__ __forceinline__ void tf2x32(uint32_t k0, uint32_t k1, uint32_t x0, uint32_t x1,
                                       uint32_t& o0, uint32_t& o1) {
    uint32_t k2 = k0 ^ k1 ^ 0x1BD11BDAu;
    x0 += k0; x1 += k1;
    x0 += x1; x1 = rotl32(x1, 13); x1 ^= x0;
    x0 += x1; x1 = rotl32(x1, 15); x1 ^= x0;
    x0 += x1; x1 = rotl32(x1, 26); x1 ^= x0;
    x0 += x1; x1 = rotl32(x1, 6);  x1 ^= x0;
    x0 += k1; x1 += k2 + 1u;
    x0 += x1; x1 = rotl32(x1, 17); x1 ^= x0;
    x0 += x1; x1 = rotl32(x1, 29); x1 ^= x0;
    x0 += x1; x1 = rotl32(x1, 16); x1 ^= x0;
    x0 += x1; x1 = rotl32(x1, 24); x1 ^= x0;
    x0 += k2; x1 += k0 + 2u;
    x0 += x1; x1 = rotl32(x1, 13); x1 ^= x0;
    x0 += x1; x1 = rotl32(x1, 15); x1 ^= x0;
    x0 += x1; x1 = rotl32(x1, 26); x1 ^= x0;
    x0 += x1; x1 = rotl32(x1, 6);  x1 ^= x0;
    x0 += k0; x1 += k1 + 3u;
    x0 += x1; x1 = rotl32(x1, 17); x1 ^= x0;
    x0 += x1; x1 = rotl32(x1, 29); x1 ^= x0;
    x0 += x1; x1 = rotl32(x1, 16); x1 ^= x0;
    x0 += x1; x1 = rotl32(x1, 24); x1 ^= x0;
    x0 += k1; x1 += k2 + 4u;
    x0 += x1; x1 = rotl32(x1, 13); x1 ^= x0;
    x0 += x1; x1 = rotl32(x1, 15); x1 ^= x0;
    x0 += x1; x1 = rotl32(x1, 26); x1 ^= x0;
    x0 += x1; x1 = rotl32(x1, 6);  x1 ^= x0;
    x0 += k2; x1 += k0 + 5u;
    o0 = x0; o1 = x1;
}

__device__ __forceinline__ uint32_t rng_m23(uint32_t k0, uint32_t k1, uint32_t i) {
    uint32_t o0, o1;
    tf2x32(k0, k1, 0u, i, o0, o1);
    return (o0 ^ o1) >> 9;
}

// ------------------- IoU (one definition -> bit-identical in both passes) ------------
__device__ __forceinline__ float iou_one(float a0, float a1, float a2, float a3,
                                         float t0, float t1, float t2, float t3) {
    float xtl = fmaxf(a0, t0), ytl = fmaxf(a1, t1);
    float xrb = fminf(a2, t2), yrb = fminf(a3, t3);
    float iw = fmaxf(xrb - xtl + 1.0f, 0.0f);
    float ih = fmaxf(yrb - ytl + 1.0f, 0.0f);
    float inter = iw * ih;
    float area1 = (a2 - a0 + 1.0f) * (a3 - a1 + 1.0f);
    float area2 = (t2 - t0 + 1.0f) * (t3 - t1 + 1.0f);
    return inter * __builtin_amdgcn_rcpf(area1 + area2 - inter);
}

// ------------------- K1: partial colmax per block (no atomics, no pre-zero) ----------
__global__ void __launch_bounds__(256) k1_colmax(const float* __restrict__ anchors,
                                                 const float* __restrict__ targets,
                                                 uint32_t* __restrict__ ws) {
    int b = blockIdx.y, j = blockIdx.x, tid = threadIdx.x;
    // folded init: zero control words + derive keys (stream order -> visible to k2).
    if (b == 0 && j == 0) {
        if (tid < 24) ws[tid] = 0u;
        if (tid == 0) {
            for (int bb = 0; bb < Bn; ++bb) {
                uint32_t o0, o1;
                tf2x32(0u, 42u, 0u, (uint32_t)bb, o0, o1);
                ws[OFF_KEYS + 2*bb] = o0; ws[OFF_KEYS + 2*bb + 1] = o1;
            }
        }
    }
    __shared__ float part[4][Mn];
    int base = j * 256 + tid;
    float4 a[APT];
    #pragma unroll
    for (int k = 0; k < APT; ++k)
        a[k] = ((const float4*)anchors)[b * Nn + base + k * STRIDE];
    float cm[Mn];
    #pragma unroll 4
    for (int t = 0; t < Mn; ++t) {
        float4 tv = ((const float4*)targets)[b * Mn + t];
        float m0 = 0.0f;
        #pragma unroll
        for (int k = 0; k < APT; ++k)
            m0 = fmaxf(m0, iou_one(a[k].x, a[k].y, a[k].z, a[k].w, tv.x, tv.y, tv.z, tv.w));
        cm[t] = m0;
    }
    #pragma unroll
    for (int t = 0; t < Mn; ++t) {
        #pragma unroll
        for (int o = 32; o > 0; o >>= 1) cm[t] = fmaxf(cm[t], __shfl_xor(cm[t], o, 64));
    }
    int wid = tid >> 6, lane = tid & 63;
    if (lane == 0) {
        #pragma unroll
        for (int t = 0; t < Mn; ++t) part[wid][t] = cm[t];
    }
    __syncthreads();
    if (tid < Mn) {
        float v = fmaxf(fmaxf(part[0][tid], part[1][tid]),
                        fmaxf(part[2][tid], part[3][tid]));
        ws[OFF_PCM + ((size_t)b * NBLK + j) * Mn + tid] = __float_as_uint(v);
    }
}

// ------------------- K2: categorize + RNG + LDS hist + segment-compacted lists ------
// Negative list: per-block private SEG-entry segment, offset from an LDS counter
// (wave-aggregated LDS atomic). ZERO global atomics on the negative path — R8's
// global ticket counter (2016 same-address round-trips/image @ ~60-115ns) was 121us.
__global__ void __launch_bounds__(256) k2_cat(const float* __restrict__ anchors,
                                              const float* __restrict__ targets,
                                              const float* __restrict__ sizes,
                                              uint32_t* __restrict__ ws) {
    int b = blockIdx.y, j = blockIdx.x, tid = threadIdx.x;
    __shared__ float cmf[Mn];
    __shared__ float redf[256];
    __shared__ uint32_t lh[1024];
    __shared__ uint32_t segcnt;
    // prologue: reduce per-block partial colmax (exact: max is assoc/comm)
    {
        int t = tid & 31, sub = tid >> 5;
        float acc = 0.0f;
        for (int jj = sub; jj < NBLK; jj += 8)
            acc = fmaxf(acc, __uint_as_float(ws[OFF_PCM + ((size_t)b * NBLK + jj) * Mn + t]));
        redf[tid] = acc;
        __syncthreads();
        if (sub == 0) {
            #pragma unroll
            for (int q = 1; q < 8; ++q) acc = fmaxf(acc, redf[t + 32 * q]);
            cmf[t] = acc;
        }
    }
    #pragma unroll
    for (int q = 0; q < 4; ++q) lh[tid + 256 * q] = 0u;
    if (tid == 0) segcnt = 0u;
    __syncthreads();

    int base = j * 256 + tid;
    float4 av[APT];
    #pragma unroll
    for (int k = 0; k < APT; ++k)
        av[k] = ((const float4*)anchors)[b * Nn + base + k * STRIDE];
    float rowmax[APT]; int ori[APT]; bool restore[APT];
    #pragma unroll
    for (int k = 0; k < APT; ++k) { rowmax[k] = -1.0f; ori[k] = 0; restore[k] = false; }
    #pragma unroll 4
    for (int t = 0; t < Mn; ++t) {
        float4 tv = ((const float4*)targets)[b * Mn + t];
        float cmv = cmf[t];   // LDS broadcast (same address across wave: free)
        #pragma unroll
        for (int k = 0; k < APT; ++k) {
            float iou = iou_one(av[k].x, av[k].y, av[k].z, av[k].w, tv.x, tv.y, tv.z, tv.w);
            if (iou > rowmax[k]) { rowmax[k] = iou; ori[k] = t; }
            restore[k] = restore[k] || (iou == cmv);
        }
    }
    float sh = sizes[b * 2 + 0], sw = sizes[b * 2 + 1];
    uint32_t key0 = ws[OFF_KEYS + 2 * b], key1 = ws[OFF_KEYS + 2 * b + 1];
    int lane = tid & 63;
    unsigned long long lt_mask = (lane == 63) ? 0x7FFFFFFFFFFFFFFFull : ((1ull << lane) - 1ull);
    uint2* nseg = (uint2*)(ws + OFF_NLIST) + (size_t)(b * NBLK + j) * SEG;
    #pragma unroll
    for (int k = 0; k < APT; ++k) {
        int i = base + k * STRIDE;
        bool inside = (av[k].x >= 0.0f) && (av[k].y >= 0.0f) &&
                      (av[k].z <= sw - 1.0f) && (av[k].w <= sh - 1.0f);
        uint32_t cat = 0;
        if (inside) {
            if (restore[k] || rowmax[k] >= FG_THR) cat = 2;
            else if (rowmax[k] < BG_THR) cat = 1;
        }
        uint32_t m = rng_m23(key0, key1, (uint32_t)i);
        // positives: global wave-aggregated ticket (rare: ~60/image -> negligible)
        unsigned long long pmask = __ballot(cat == 2u);
        if (pmask) {
            int leader = __ffsll((long long)pmask) - 1;
            uint32_t bb = 0;
            if (lane == leader) bb = atomicAdd(&ws[OFF_POSCNT + b], (uint32_t)__popcll(pmask));
            bb = __shfl(bb, leader, 64);
            if (cat == 2u) {
                uint32_t p = bb + (uint32_t)__popcll(pmask & lt_mask);
                if (p < POS_CAP)
                    ((uint2*)(ws + OFF_PLIST))[(size_t)b * POS_CAP + p] =
                        make_uint2(m, (uint32_t)i | ((uint32_t)ori[k] << 17));
            }
        }
        // negatives: LDS-counter segment compaction (no global atomics)
        unsigned long long nmask = __ballot(cat == 1u);
        if (nmask) {
            int leader = __ffsll((long long)nmask) - 1;
            uint32_t bb = 0;
            if (lane == leader) bb = atomicAdd(&segcnt, (uint32_t)__popcll(nmask));
            bb = __shfl(bb, leader, 64);
            if (cat == 1u) {
                uint32_t p = bb + (uint32_t)__popcll(nmask & lt_mask);
                nseg[p] = make_uint2(m, (uint32_t)i);
                atomicAdd(&lh[m >> 13], 1u);
            }
        }
    }
    __syncthreads();
    uint32_t* slice = ws + OFF_PHIST + ((size_t)b * NBLK + j) * 1024;
    #pragma unroll
    for (int q = 0; q < 4; ++q) slice[tid + 256 * q] = lh[tid + 256 * q];
    if (tid == 0) ws[OFF_NSEGC + b * NBLK + j] = segcnt;
}

// ------------------- K2.5: reduce slices + suffix scan + boundary -------------------
__global__ void __launch_bounds__(256) k25_bound(uint32_t* __restrict__ ws) {
    int b = blockIdx.x, t = threadIdx.x;
    __shared__ uint32_t csum[256];
    uint4 h = make_uint4(0, 0, 0, 0);
    const uint32_t* ph = ws + OFF_PHIST + (size_t)b * NBLK * 1024;
    for (int s = 0; s < NBLK; ++s) {
        uint4 v = ((const uint4*)(ph + (size_t)s * 1024))[t];
        h.x += v.x; h.y += v.y; h.z += v.z; h.w += v.w;
    }
    uint32_t sum = h.x + h.y + h.z + h.w;
    csum[t] = sum;
    __syncthreads();
    for (int off = 1; off < 256; off <<= 1) {
        uint32_t mine = csum[t];
        uint32_t add = (t + off < 256) ? csum[t + off] : 0u;
        __syncthreads();
        csum[t] = mine + add;
        __syncthreads();
    }
    uint32_t pc = ws[OFF_POSCNT + b];
    int num_pos = (pc < (uint32_t)NPOSMAX) ? (int)pc : NPOSMAX;
    int k_neg = NPERIM - num_pos;
    uint32_t total = csum[0];
    if ((int)total < k_neg) {
        if (t == 0) {
            ws[OFF_BOUND + b] = 0xFFFFFFFFu;
            ws[OFF_NEED + b] = 0u;
            atomicAdd(&ws[OFF_COUNT], (uint32_t)(num_pos + (int)total));
        }
        return;
    }
    uint32_t incl = csum[t];
    uint32_t next = (t < 255) ? csum[t + 1] : 0u;
    if ((int)incl >= k_neg && (int)next < k_neg) {
        int cum = (int)next;
        uint32_t hv[4] = { h.x, h.y, h.z, h.w };
        int boundary = -1, needed = 0;
        #pragma unroll
        for (int q = 3; q >= 0; --q) {
            int c = (int)hv[q];
            if (cum + c >= k_neg) { boundary = 4 * t + q; needed = k_neg - cum; break; }
            cum += c;
        }
        ws[OFF_BOUND + b] = (uint32_t)boundary;
        ws[OFF_NEED + b] = (uint32_t)needed;
        atomicAdd(&ws[OFF_COUNT], (uint32_t)(num_pos + k_neg));
    }
}

// ------------------- K3: scan per-block negative segments -------------------
__global__ void __launch_bounds__(256) k3_neg(const float* __restrict__ logits,
                                              uint32_t* __restrict__ ws) {
    int b = blockIdx.y, j = blockIdx.x;
    int bd = (int)(int32_t)ws[OFF_BOUND + b];                 // uniform
    int cnt = (int)ws[OFF_NSEGC + b * NBLK + j];              // uniform
    const uint2* nseg = (const uint2*)(ws + OFF_NLIST) + (size_t)(b * NBLK + j) * SEG;
    float local = 0.0f;
    for (int idx = (int)threadIdx.x; idx < cnt; idx += 256) {
        uint2 e = nseg[idx];
        int bk = (int)(e.x >> 13);
        if (bk > bd) {
            int i = (int)e.y;
            int a = i % An, hw = i / An;
            float l = logits[(b * An + a) * HWn + hw];
            local += fmaxf(l, 0.0f) + log1pf(expf(-fabsf(l)));   // BCE(l,0)
        } else if (bk == bd) {
            uint32_t q = atomicAdd(&ws[OFF_BNDCNT + b], 1u);    // rare (~100/image)
            if (q < BND_CAP)
                ((uint2*)(ws + OFF_BLIST))[(size_t)b * BND_CAP + q] = e;
        }
    }
    __shared__ float red[256];
    red[threadIdx.x] = local;
    __syncthreads();
    for (int s = 128; s > 0; s >>= 1) {
        if ((int)threadIdx.x < s) red[threadIdx.x] += red[threadIdx.x + s];
        __syncthreads();
    }
    if (threadIdx.x == 0 && red[0] != 0.0f) atomicAdd((float*)&ws[OFF_CLS], red[0]);
}

// ------------------- K4: per-image finalize + output -------------------
__device__ __forceinline__ bool sel_less(uint2 a, uint2 b) {
    // larger priority m first; tie -> smaller index (JAX top_k order)
    return (a.x > b.x) || (a.x == b.x && a.y < b.y);
}

__device__ void bitonic_sort_shared(uint2* buf, int n) {   // n = pow2
    for (int k = 2; k <= n; k <<= 1) {
        for (int j = k >> 1; j > 0; j >>= 1) {
            for (int t = (int)threadIdx.x; t < n; t += 256) {
                int ixj = t ^ j;
                if (ixj > t) {
                    uint2 x = buf[t], y = buf[ixj];
                    bool up = ((t & k) == 0);
                    bool sw = up ? sel_less(y, x) : sel_less(x, y);
                    if (sw) { buf[t] = y; buf[ixj] = x; }
                }
            }
            __syncthreads();
        }
    }
}

__global__ void __launch_bounds__(256) k4_final(const float* __restrict__ anchors,
                                                const float* __restrict__ targets,
                                                const float* __restrict__ logits,
                                                const float* __restrict__ bregs,
                                                uint32_t* __restrict__ ws,
                                                float* __restrict__ out) {
    int b = blockIdx.x, tid = threadIdx.x;
    __shared__ uint2 buf[BND_CAP];
    __shared__ float red[256];
    float cls = 0.0f, reg = 0.0f;

    uint32_t pcu = ws[OFF_POSCNT + b];
    int pc = (pcu < (uint32_t)POS_CAP) ? (int)pcu : POS_CAP;
    const uint2* plist = (const uint2*)(ws + OFF_PLIST) + (size_t)b * POS_CAP;
    int psel = (pc < NPOSMAX) ? pc : NPOSMAX;
    bool use_buf = false;
    if (pc > NPOSMAX) {
        int n = (pc < BND_CAP) ? pc : BND_CAP;
        for (int t = tid; t < n; t += 256) buf[t] = plist[t];
        int npad = 1; while (npad < n) npad <<= 1;
        for (int t = tid; t < npad; t += 256) if (t >= n) buf[t] = make_uint2(0u, 0xFFFFFFFFu);
        __syncthreads();
        bitonic_sort_shared(buf, npad);
        use_buf = true;
        psel = (NPOSMAX < n) ? NPOSMAX : n;
    }
    for (int t = tid; t < psel; t += 256) {
        uint32_t packed = use_buf ? buf[t].y : plist[t].y;
        int i = (int)(packed & 0x1FFFFu);
        int ori = (int)(packed >> 17);
        int a = i % An, hw = i / An;
        float l = logits[(b * An + a) * HWn + hw];
        cls += fmaxf(l, 0.0f) - l + log1pf(expf(-fabsf(l)));   // BCE(l,1)
        float4 av = ((const float4*)anchors)[b * Nn + i];
        float4 tv = ((const float4*)targets)[b * Mn + ori];
        float aws = av.z - av.x + 1.0f, ahs = av.w - av.y + 1.0f;
        float axc = av.x + 0.5f * aws, ayc = av.y + 0.5f * ahs;
        float tws = tv.z - tv.x + 1.0f, ths = tv.w - tv.y + 1.0f;
        float txc = tv.x + 0.5f * tws, tyc = tv.y + 0.5f * ths;
        float off0 = (txc - axc) / aws;
        float off1 = (tyc - ayc) / ahs;
        float off2 = logf(tws / aws);
        float off3 = logf(ths / ahs);
        float br0 = bregs[(b * 12 + a * 4 + 0) * HWn + hw];
        float br1 = bregs[(b * 12 + a * 4 + 1) * HWn + hw];
        float br2 = bregs[(b * 12 + a * 4 + 2) * HWn + hw];
        float br3 = bregs[(b * 12 + a * 4 + 3) * HWn + hw];
        float d;
        d = fabsf(br0 - off0); reg += (d < BETA) ? 0.5f * d * d / BETA : d - 0.5f * BETA;
        d = fabsf(br1 - off1); reg += (d < BETA) ? 0.5f * d * d / BETA : d - 0.5f * BETA;
        d = fabsf(br2 - off2); reg += (d < BETA) ? 0.5f * d * d / BETA : d - 0.5f * BETA;
        d = fabsf(br3 - off3); reg += (d < BETA) ? 0.5f * d * d / BETA : d - 0.5f * BETA;
    }
    __syncthreads();

    int need = (int)ws[OFF_NEED + b];
    if (need > 0) {
        uint32_t nbu = ws[OFF_BNDCNT + b];
        int nb = (nbu < (uint32_t)BND_CAP) ? (int)nbu : BND_CAP;
        const uint2* blist = (const uint2*)(ws + OFF_BLIST) + (size_t)b * BND_CAP;
        for (int t = tid; t < nb; t += 256) buf[t] = blist[t];
        int npad = 1; while (npad < nb) npad <<= 1;
        for (int t = tid; t < npad; t += 256) if (t >= nb) buf[t] = make_uint2(0u, 0xFFFFFFFFu);
        __syncthreads();
        bitonic_sort_shared(buf, npad);
        int sel = (need < nb) ? need : nb;
        for (int t = tid; t < sel; t += 256) {
            int i = (int)buf[t].y;
            int a = i % An, hw = i / An;
            float l = logits[(b * An + a) * HWn + hw];
            cls += fmaxf(l, 0.0f) + log1pf(expf(-fabsf(l)));   // BCE(l,0)
        }
    }

    red[tid] = cls;
    __syncthreads();
    for (int s = 128; s > 0; s >>= 1) {
        if (tid < s) red[tid] += red[tid + s];
        __syncthreads();
    }
    if (tid == 0 && red[0] != 0.0f) atomicAdd((float*)&ws[OFF_CLS], red[0]);
    __syncthreads();
    red[tid] = reg;
    __syncthreads();
    for (int s = 128; s > 0; s >>= 1) {
        if (tid < s) red[tid] += red[tid + s];
        __syncthreads();
    }
    if (tid == 0) {
        if (red[0] != 0.0f) atomicAdd((float*)&ws[OFF_REG], red[0]);
        __threadfence();
        uint32_t old = atomicAdd(&ws[OFF_DONE], 1u);
        if (old == Bn - 1) {
            float cls_tot = __uint_as_float(atomicAdd(&ws[OFF_CLS], 0u));
            float reg_tot = __uint_as_float(atomicAdd(&ws[OFF_REG], 0u));
            float cnt = (float)atomicAdd(&ws[OFF_COUNT], 0u);
            out[0] = cls_tot / cnt;
            out[1] = reg_tot / cnt;
        }
    }
}

extern "C" void kernel_launch(void* const* d_in, const int* in_sizes, int n_in,
                              void* d_out, int out_size, void* d_ws, size_t ws_size,
                              hipStream_t stream) {
    const float* anchors = (const float*)d_in[0];   // [B, N, 4]
    const float* logits  = (const float*)d_in[1];   // [B, A, H, W]
    const float* bregs   = (const float*)d_in[2];   // [B, 4A, H, W]
    const float* sizes   = (const float*)d_in[3];   // [B, 2]
    const float* targets = (const float*)d_in[4];   // [B, M, 4]
    float* out = (float*)d_out;
    uint32_t* ws = (uint32_t*)d_ws;

    k1_colmax<<<dim3(NBLK, Bn), dim3(256), 0, stream>>>(anchors, targets, ws);
    k2_cat<<<dim3(NBLK, Bn), dim3(256), 0, stream>>>(anchors, targets, sizes, ws);
    k25_bound<<<dim3(Bn), dim3(256), 0, stream>>>(ws);
    k3_neg<<<dim3(NBLK, Bn), dim3(256), 0, stream>>>(logits, ws);
    k4_final<<<dim3(Bn), dim3(256), 0, stream>>>(anchors, targets, logits, bregs, ws, out);
}